// Round 2
// baseline (18143.092 us; speedup 1.0000x reference)
//
#include <hip/hip_runtime.h>
#include <stdint.h>

// ---------------------------------------------------------------------------
// AWD-LSTM eval forward.  T=256, B=256, H=1024, FEAT=319 (=300+7+12), C=13.
// Insight: layer1's recurrent carry is ignored by the reference (it uses
// h0n[::-1], c0n[::-1]) -> only layer0 is sequential; layer1+decoder are
// parallel over all 65536 rows.
// All GEMMs: bf16 MFMA 16x16x32, f32 accum.  Weights repacked gate-interleaved
// (col 4j+p = gate p of unit j) so the LSTM cell is fused into the epilogue.
//
// Two ws budgets (unknown ws_size -> choose at launch):
//   Path A (~474 MB): store full h0/c0/h1 trajectories; layer1 = ONE big GEMM.
//   Path B (~73 MB):  2-slot h0 ring, per-step layer1 GEMM + decode.
//   ws too small for B: launch nothing (out stays poisoned -> diagnosable).
// ---------------------------------------------------------------------------

typedef __attribute__((ext_vector_type(8))) short bf16x8;
typedef __attribute__((ext_vector_type(4))) float f32x4;

__device__ __forceinline__ uint16_t f2bf(float f) {
  uint32_t u = __float_as_uint(f);
  u += 0x7fffu + ((u >> 16) & 1u);
  return (uint16_t)(u >> 16);
}
__device__ __forceinline__ float bf2f(uint16_t h) {
  return __uint_as_float(((uint32_t)h) << 16);
}
__device__ __forceinline__ float sigmoidf_(float x) {
  return __builtin_amdgcn_rcpf(1.0f + __expf(-x));
}
__device__ __forceinline__ float tanhf_(float x) {
  return 1.0f - 2.0f * __builtin_amdgcn_rcpf(__expf(2.0f * x) + 1.0f);
}
__device__ __forceinline__ void gload_lds16(const void* g, void* l) {
  __builtin_amdgcn_global_load_lds(
      (const __attribute__((address_space(1))) void*)g,
      (__attribute__((address_space(3))) void*)l, 16, 0, 0);
}
// LDS tile layout: row-major [rows][32 k] bf16, the four 16B chunks of each
// row stored permuted: chunk_pos = chunk ^ ((row>>1)&3)  -> ~2-way banks
__device__ __forceinline__ bf16x8 lds_frag(const uint16_t* base, int row, int kc) {
  const uint16_t* p = base + row * 32 + ((kc ^ ((row >> 1) & 3)) << 3);
  return *(const bf16x8*)p;
}
__device__ __forceinline__ f32x4 mfma16(bf16x8 a, bf16x8 b, f32x4 c) {
  return __builtin_amdgcn_mfma_f32_16x16x32_bf16(a, b, c, 0, 0, 0);
}

// ---------------- weight prep ----------------
__global__ __launch_bounds__(256) void k_prep_w0(
    const float* __restrict__ wi0, const float* __restrict__ bi0,
    const float* __restrict__ wh0, const float* __restrict__ bh0,
    uint16_t* __restrict__ W0c, float* __restrict__ b0) {
  int r = blockIdx.x;            // interleaved output row: unit j, gate p
  int p = r & 3, j = r >> 2;
  int src = p * 1024 + j;
  const float* wi = wi0 + (size_t)src * 319;
  const float* wh = wh0 + (size_t)src * 1024;
  uint16_t* dst = W0c + (size_t)r * 1344;
  for (int k = threadIdx.x; k < 1344; k += 256) {
    float v;
    if (k < 319) v = wi[k];
    else if (k == 319) v = 0.0f;
    else v = wh[k - 320];
    dst[k] = f2bf(v);
  }
  if (threadIdx.x == 0) b0[r] = bi0[src] + bh0[src];
}

__global__ __launch_bounds__(256) void k_prep_w1(
    const float* __restrict__ wi1, const float* __restrict__ bi1,
    const float* __restrict__ wh1, const float* __restrict__ bh1,
    uint16_t* __restrict__ W1c, float* __restrict__ b1) {
  int r = blockIdx.x;
  int p = r & 3, j = r >> 2;
  int src = p * 1024 + j;
  const float* wi = wi1 + (size_t)src * 1024;
  const float* wh = wh1 + (size_t)src * 1024;
  uint16_t* dst = W1c + (size_t)r * 2048;
  for (int k = threadIdx.x; k < 2048; k += 256) {
    float v = (k < 1024) ? wi[k] : wh[k - 1024];
    dst[k] = f2bf(v);
  }
  if (threadIdx.x == 0) b1[r] = bi1[src] + bh1[src];
}

__global__ __launch_bounds__(256) void k_init(
    const float* __restrict__ h_init, const float* __restrict__ c_init,
    uint16_t* __restrict__ h0_slot0, float* __restrict__ c_state) {
  int i = blockIdx.x * 256 + threadIdx.x;  // 262144 = 256*1024
  h0_slot0[i] = f2bf(h_init[i]);           // layer0 slice of h_init
  c_state[i] = c_init[i];
}

// ---------------- embedding + concat -> x_bf ----------------
__global__ __launch_bounds__(256) void k_embed(
    const int* __restrict__ tokens, const float* __restrict__ casing,
    const float* __restrict__ pos, const float* __restrict__ emb,
    uint16_t* __restrict__ x_bf) {
  int row = blockIdx.x * 4 + (threadIdx.x >> 6);  // (t*256+b)
  int l = threadIdx.x & 63;
  int tok = tokens[row];
  const float* er = emb + (size_t)tok * 300;
  uint16_t* xr = x_bf + (size_t)row * 320;
#pragma unroll
  for (int c0 = 0; c0 < 320; c0 += 64) {
    int c = c0 + l;
    float v;
    if (c < 300) v = er[c];
    else if (c < 307) v = casing[(size_t)row * 7 + (c - 300)];
    else if (c < 319) v = pos[(size_t)row * 12 + (c - 307)];
    else v = 0.0f;
    xr[c] = f2bf(v);
  }
}

// ---------------- layer0 sequential step ----------------
// GEMM [256 x 1344] @ [4096 x 1344]^T, tile 64x64, 4 waves (2x2), fused cell.
// x_t: [256][320] bf16 for this step; h0_in/h0_out/c0_out: [256][1024] slots.
__global__ __launch_bounds__(256) void k_step(
    const uint16_t* __restrict__ x_t, const uint16_t* __restrict__ W0c,
    const float* __restrict__ b0, const uint16_t* __restrict__ h0_in,
    uint16_t* __restrict__ h0_out, uint16_t* __restrict__ c0_out,
    float* __restrict__ c_state) {
  __shared__ __align__(16) uint16_t As[64 * 32];
  __shared__ __align__(16) uint16_t Bs[64 * 32];
  __shared__ __align__(16) float epi[4][16][40];
  int tid = threadIdx.x;
  int w = tid >> 6, l = tid & 63;
  int wr = w >> 1, wc = w & 1;
  int Mb = blockIdx.x * 64;   // batch tile
  int Nb = blockIdx.y * 64;   // output-col tile (gate-interleaved)
  f32x4 acc[2][2] = {};

  // staging: wave w stages rows w*16..+16 of both tiles; lane -> (row, chunk)
  int srow = w * 16 + (l >> 2);
  int sc = (l & 3) ^ ((l >> 3) & 3);  // global chunk for this lane's LDS slot
  int bA = Mb + srow;
  const uint16_t* xrow = x_t + (size_t)bA * 320;
  const uint16_t* hrow = h0_in + (size_t)bA * 1024;
  const uint16_t* wrow = W0c + (size_t)(Nb + srow) * 1344;
  uint16_t* AsW = As + w * 512;
  uint16_t* BsW = Bs + w * 512;

  for (int kt = 0; kt < 42; ++kt) {
    int kg = kt * 32 + sc * 8;
    const uint16_t* srcA = (kg < 320) ? (xrow + kg) : (hrow + (kg - 320));
    gload_lds16(srcA, AsW);
    gload_lds16(wrow + kg, BsW);
    __syncthreads();
    bf16x8 a0 = lds_frag(As, wr * 32 + (l & 15), l >> 4);
    bf16x8 a1 = lds_frag(As, wr * 32 + 16 + (l & 15), l >> 4);
    bf16x8 q0 = lds_frag(Bs, wc * 32 + (l & 15), l >> 4);
    bf16x8 q1 = lds_frag(Bs, wc * 32 + 16 + (l & 15), l >> 4);
    acc[0][0] = mfma16(a0, q0, acc[0][0]);
    acc[0][1] = mfma16(a0, q1, acc[0][1]);
    acc[1][0] = mfma16(a1, q0, acc[1][0]);
    acc[1][1] = mfma16(a1, q1, acc[1][1]);
    __syncthreads();
  }

  // fused LSTM cell epilogue (per-wave LDS scratch, no cross-wave barrier)
  int jbase = (Nb + wc * 32) >> 2;
#pragma unroll
  for (int m = 0; m < 2; ++m) {
#pragma unroll
    for (int n = 0; n < 2; ++n)
#pragma unroll
      for (int r = 0; r < 4; ++r)
        epi[w][(l >> 4) * 4 + r][n * 16 + (l & 15)] = acc[m][n][r];
    asm volatile("s_waitcnt lgkmcnt(0)" ::: "memory");
#pragma unroll
    for (int it = 0; it < 2; ++it) {
      int pp = it * 64 + l;
      int rr = pp >> 3, j = pp & 7;
      f32x4 q = *(const f32x4*)&epi[w][rr][j * 4];
      int colg = Nb + wc * 32 + j * 4;
      f32x4 bv = *(const f32x4*)&b0[colg];
      float vi = sigmoidf_(q[0] + bv[0]);
      float vf = sigmoidf_(q[1] + bv[1]);
      float vo = sigmoidf_(q[2] + bv[2]);
      float vg = tanhf_(q[3] + bv[3]);
      int bg = Mb + wr * 32 + m * 16 + rr;
      int jg = jbase + j;
      size_t sidx = (size_t)bg * 1024 + jg;
      float cold = c_state[sidx];
      float cn = vf * cold + vi * vg;
      float hh = vo * tanhf_(cn);
      c_state[sidx] = cn;
      c0_out[sidx] = f2bf(cn);
      h0_out[sidx] = f2bf(hh);
    }
    asm volatile("s_waitcnt lgkmcnt(0)" ::: "memory");
  }
}

// ---------------- layer1 GEMM (strided over t) ----------------
// [rows x 2048] @ [4096 x 2048]^T; A row (t,b) = [h0(t,b) | h0(t,255-b)].
// tile 128x128, 4 waves (2x2) x (4x4 frags), fused cell epilogue.
// h0_src + t*h0_ts points at the h0n slot for step t (256x1024 bf16).
__global__ __launch_bounds__(256) void k_l1gemm(
    const uint16_t* __restrict__ h0_src, size_t h0_ts,
    const uint16_t* __restrict__ W1c, const float* __restrict__ b1,
    const uint16_t* __restrict__ c0_src, size_t c0_ts,
    uint16_t* __restrict__ h1_out, size_t h1_ts) {
  __shared__ __align__(16) uint16_t As[128 * 32];
  __shared__ __align__(16) uint16_t Bs[128 * 32];
  __shared__ __align__(16) float epi[4][16][68];
  int tid = threadIdx.x;
  int w = tid >> 6, l = tid & 63;
  int wr = w >> 1, wc = w & 1;
  int Mb = blockIdx.y * 128, Nb = blockIdx.x * 128;
  int t = Mb >> 8;
  int bbase = Mb & 255;  // 0 or 128
  const uint16_t* hrow = h0_src + (size_t)t * h0_ts;
  f32x4 acc[4][4] = {};

  int sc = (l & 3) ^ ((l >> 3) & 3);
  int srow0 = (w * 2 + 0) * 16 + (l >> 2);
  int srow1 = (w * 2 + 1) * 16 + (l >> 2);
  const uint16_t* hA0n = hrow + (size_t)(bbase + srow0) * 1024;
  const uint16_t* hA0f = hrow + (size_t)(255 - (bbase + srow0)) * 1024;
  const uint16_t* hA1n = hrow + (size_t)(bbase + srow1) * 1024;
  const uint16_t* hA1f = hrow + (size_t)(255 - (bbase + srow1)) * 1024;
  const uint16_t* wB0 = W1c + (size_t)(Nb + srow0) * 2048;
  const uint16_t* wB1 = W1c + (size_t)(Nb + srow1) * 2048;
  uint16_t* AsW0 = As + (w * 2 + 0) * 512;
  uint16_t* AsW1 = As + (w * 2 + 1) * 512;
  uint16_t* BsW0 = Bs + (w * 2 + 0) * 512;
  uint16_t* BsW1 = Bs + (w * 2 + 1) * 512;

  for (int kt = 0; kt < 64; ++kt) {
    int kg = kt * 32 + sc * 8;
    const uint16_t* sA0 = (kg < 1024) ? (hA0n + kg) : (hA0f + (kg - 1024));
    const uint16_t* sA1 = (kg < 1024) ? (hA1n + kg) : (hA1f + (kg - 1024));
    gload_lds16(sA0, AsW0);
    gload_lds16(sA1, AsW1);
    gload_lds16(wB0 + kg, BsW0);
    gload_lds16(wB1 + kg, BsW1);
    __syncthreads();
    bf16x8 a[4], q[4];
#pragma unroll
    for (int m = 0; m < 4; ++m) a[m] = lds_frag(As, wr * 64 + m * 16 + (l & 15), l >> 4);
#pragma unroll
    for (int n = 0; n < 4; ++n) q[n] = lds_frag(Bs, wc * 64 + n * 16 + (l & 15), l >> 4);
#pragma unroll
    for (int m = 0; m < 4; ++m)
#pragma unroll
      for (int n = 0; n < 4; ++n) acc[m][n] = mfma16(a[m], q[n], acc[m][n]);
    __syncthreads();
  }

  int jbase = (Nb + wc * 64) >> 2;
#pragma unroll
  for (int m = 0; m < 4; ++m) {
#pragma unroll
    for (int n = 0; n < 4; ++n)
#pragma unroll
      for (int r = 0; r < 4; ++r)
        epi[w][(l >> 4) * 4 + r][n * 16 + (l & 15)] = acc[m][n][r];
    asm volatile("s_waitcnt lgkmcnt(0)" ::: "memory");
#pragma unroll
    for (int it = 0; it < 4; ++it) {
      int pp = it * 64 + l;
      int rr = pp >> 4, j = pp & 15;
      f32x4 q = *(const f32x4*)&epi[w][rr][j * 4];
      int colg = Nb + wc * 64 + j * 4;
      f32x4 bv = *(const f32x4*)&b1[colg];
      float vi = sigmoidf_(q[0] + bv[0]);
      float vf = sigmoidf_(q[1] + bv[1]);
      float vo = sigmoidf_(q[2] + bv[2]);
      float vg = tanhf_(q[3] + bv[3]);
      int rowl = wr * 64 + m * 16 + rr;
      int b = bbase + rowl;
      int jg = jbase + j;
      float c0v = bf2f(c0_src[(size_t)t * c0_ts + (size_t)(255 - b) * 1024 + jg]);
      float cn = vf * c0v + vi * vg;
      float hh = vo * tanhf_(cn);
      h1_out[(size_t)t * h1_ts + (size_t)b * 1024 + jg] = f2bf(hh);
    }
    asm volatile("s_waitcnt lgkmcnt(0)" ::: "memory");
  }
}

// ---------------- decoder ----------------
__global__ __launch_bounds__(256) void k_decode(
    const uint16_t* __restrict__ h0_src, size_t h0_ts,
    const uint16_t* __restrict__ h1_src, size_t h1_ts,
    const float* __restrict__ dec_w, const float* __restrict__ dec_b,
    float* __restrict__ out, int row0) {
  int row = row0 + blockIdx.x * 4 + (threadIdx.x >> 6);
  int l = threadIdx.x & 63;
  int t = row >> 8, b = row & 255;
  const uint16_t* h0 = h0_src + (size_t)t * h0_ts + (size_t)b * 1024;
  const uint16_t* h1 = h1_src + (size_t)t * h1_ts + (size_t)b * 1024;
  float acc[13];
#pragma unroll
  for (int c = 0; c < 13; ++c) acc[c] = 0.0f;
#pragma unroll
  for (int part = 0; part < 2; ++part) {
    const uint16_t* h = part ? h1 : h0;
    const float* wb = dec_w + part * 1024 + (size_t)l * 16;
    float hv[16];
    const bf16x8* hp = (const bf16x8*)(h + l * 16);
    bf16x8 v0 = hp[0];
    bf16x8 v1 = hp[1];
#pragma unroll
    for (int jj = 0; jj < 8; ++jj) {
      hv[jj] = bf2f((uint16_t)v0[jj]);
      hv[8 + jj] = bf2f((uint16_t)v1[jj]);
    }
#pragma unroll
    for (int c = 0; c < 13; ++c) {
      const float* wc = wb + (size_t)c * 2048;
      float s = 0.0f;
#pragma unroll
      for (int jj = 0; jj < 16; ++jj) s += hv[jj] * wc[jj];
      acc[c] += s;
    }
  }
#pragma unroll
  for (int c = 0; c < 13; ++c) {
    float v = acc[c];
#pragma unroll
    for (int off = 32; off > 0; off >>= 1) v += __shfl_xor(v, off, 64);
    acc[c] = v;
  }
  if (l == 0) {
    float* orow = out + (size_t)row * 13;
#pragma unroll
    for (int c = 0; c < 13; ++c) orow[c] = acc[c] + dec_b[c];
  }
}

// ---------------- host ----------------
extern "C" void kernel_launch(void* const* d_in, const int* in_sizes, int n_in,
                              void* d_out, int out_size, void* d_ws, size_t ws_size,
                              hipStream_t stream) {
  const int* tokens = (const int*)d_in[0];
  const float* casing = (const float*)d_in[1];
  const float* pos = (const float*)d_in[2];
  const float* emb = (const float*)d_in[3];
  const float* wi0 = (const float*)d_in[4];
  const float* bi0 = (const float*)d_in[5];
  const float* wh0 = (const float*)d_in[6];
  const float* bh0 = (const float*)d_in[7];
  const float* wi1 = (const float*)d_in[8];
  const float* bi1 = (const float*)d_in[9];
  const float* wh1 = (const float*)d_in[10];
  const float* bh1 = (const float*)d_in[11];
  const float* dec_w = (const float*)d_in[12];
  const float* dec_b = (const float*)d_in[13];
  const float* h_init = (const float*)d_in[14];
  const float* c_init = (const float*)d_in[15];
  float* out = (float*)d_out;
  (void)in_sizes; (void)n_in; (void)out_size;

  char* ws = (char*)d_ws;
  size_t off = 0;
  auto alloc = [&](size_t bytes) {
    char* p = ws + off;
    off += (bytes + 255) & ~(size_t)255;
    return p;
  };
  // shared by both paths (~70.8 MB)
  uint16_t* W0c = (uint16_t*)alloc(4096ull * 1344 * 2);
  float* b0 = (float*)alloc(4096 * 4);
  uint16_t* W1c = (uint16_t*)alloc(4096ull * 2048 * 2);
  float* b1 = (float*)alloc(4096 * 4);
  uint16_t* x_bf = (uint16_t*)alloc(65536ull * 320 * 2);
  float* c_st = (float*)alloc(262144ull * 4);

  const size_t SLOT = 262144;  // 256*1024 elements
  const size_t PATH_A_NEED = off + (257ull + 256 + 256) * SLOT * 2 + 4096;
  const size_t PATH_B_NEED = off + 4ull * SLOT * 2 + 4096;

  // common prep
  auto prep = [&]() {
    k_prep_w0<<<4096, 256, 0, stream>>>(wi0, bi0, wh0, bh0, W0c, b0);
    k_prep_w1<<<4096, 256, 0, stream>>>(wi1, bi1, wh1, bh1, W1c, b1);
    k_embed<<<16384, 256, 0, stream>>>(tokens, casing, pos, emb, x_bf);
  };

  if (ws_size >= PATH_A_NEED) {
    // ---- Path A: full trajectories, one big layer1 GEMM ----
    uint16_t* h0_all = (uint16_t*)alloc(257ull * SLOT * 2);
    uint16_t* c0_all = (uint16_t*)alloc(256ull * SLOT * 2);
    uint16_t* h1_all = (uint16_t*)alloc(256ull * SLOT * 2);
    prep();
    k_init<<<1024, 256, 0, stream>>>(h_init, c_init, h0_all, c_st);
    for (int t = 0; t < 256; ++t)
      k_step<<<dim3(4, 64), 256, 0, stream>>>(
          x_bf + (size_t)t * 81920, W0c, b0,
          h0_all + (size_t)t * SLOT, h0_all + (size_t)(t + 1) * SLOT,
          c0_all + (size_t)t * SLOT, c_st);
    k_l1gemm<<<dim3(32, 512), 256, 0, stream>>>(
        h0_all + SLOT, SLOT, W1c, b1, c0_all, SLOT, h1_all, SLOT);
    k_decode<<<16384, 256, 0, stream>>>(
        h0_all + SLOT, SLOT, h1_all, SLOT, dec_w, dec_b, out, 0);
  } else if (ws_size >= PATH_B_NEED) {
    // ---- Path B: 2-slot h0 ring, per-step layer1 + decode ----
    uint16_t* h0r = (uint16_t*)alloc(2ull * SLOT * 2);
    uint16_t* c0s = (uint16_t*)alloc(SLOT * 2);
    uint16_t* h1s = (uint16_t*)alloc(SLOT * 2);
    prep();
    k_init<<<1024, 256, 0, stream>>>(h_init, c_init, h0r, c_st);
    for (int t = 0; t < 256; ++t) {
      const uint16_t* hin = h0r + (size_t)(t & 1) * SLOT;
      uint16_t* hout = h0r + (size_t)((t + 1) & 1) * SLOT;
      k_step<<<dim3(4, 64), 256, 0, stream>>>(
          x_bf + (size_t)t * 81920, W0c, b0, hin, hout, c0s, c_st);
      k_l1gemm<<<dim3(32, 2), 256, 0, stream>>>(
          hout, 0, W1c, b1, c0s, 0, h1s, 0);
      k_decode<<<64, 256, 0, stream>>>(
          hout, 0, h1s, 0, dec_w, dec_b, out, t * 256);
    }
  }
  // else: ws too small for any path -> launch nothing; harness will report
  // a poisoned-output absmax (diagnostic: ws_size < ~74 MB).
}

// Round 3
// 6628.425 us; speedup vs baseline: 2.7372x; 2.7372x over previous
//
#include <hip/hip_runtime.h>
#include <stdint.h>

// ---------------------------------------------------------------------------
// AWD-LSTM eval forward.  T=256, B=256, H=1024, FEAT=319 (=300+7+12), C=13.
// Layer1's recurrent carry is ignored by the reference (uses h0n[::-1],
// c0n[::-1]) -> only layer0 is sequential; layer1+decoder are parallel.
// Chunked pipeline: CH timesteps of layer0, then one layer1 GEMM over the
// chunk (grid 32 x 2CH -> full CU occupancy) + chunked decode.  CH chosen
// from ws_size at launch (ring buffers; CH=64 needs ~172 MB, CH=8 ~84 MB).
// GEMMs: bf16 MFMA 16x16x32, f32 accum; weights gate-interleaved
// (col 4j+p = gate p of unit j) so the LSTM cell fuses into the epilogue.
// ---------------------------------------------------------------------------

typedef __attribute__((ext_vector_type(8))) short bf16x8;
typedef __attribute__((ext_vector_type(4))) float f32x4;

#define SLOT 262144ull  // 256*1024 elements per (B,H) slab

__device__ __forceinline__ uint16_t f2bf(float f) {
  uint32_t u = __float_as_uint(f);
  u += 0x7fffu + ((u >> 16) & 1u);
  return (uint16_t)(u >> 16);
}
__device__ __forceinline__ float bf2f(uint16_t h) {
  return __uint_as_float(((uint32_t)h) << 16);
}
__device__ __forceinline__ float sigmoidf_(float x) {
  return __builtin_amdgcn_rcpf(1.0f + __expf(-x));
}
__device__ __forceinline__ float tanhf_(float x) {
  return 1.0f - 2.0f * __builtin_amdgcn_rcpf(__expf(2.0f * x) + 1.0f);
}
__device__ __forceinline__ void gload_lds16(const void* g, void* l) {
  __builtin_amdgcn_global_load_lds(
      (const __attribute__((address_space(1))) void*)g,
      (__attribute__((address_space(3))) void*)l, 16, 0, 0);
}
// LDS tile: row-major [rows][32 k] bf16; four 16B chunks of each row stored
// permuted: chunk_pos = chunk ^ ((row>>1)&3)  -> ~2-way banks (free)
__device__ __forceinline__ bf16x8 lds_frag(const uint16_t* base, int row, int kc) {
  const uint16_t* p = base + row * 32 + ((kc ^ ((row >> 1) & 3)) << 3);
  return *(const bf16x8*)p;
}
__device__ __forceinline__ f32x4 mfma16(bf16x8 a, bf16x8 b, f32x4 c) {
  return __builtin_amdgcn_mfma_f32_16x16x32_bf16(a, b, c, 0, 0, 0);
}

// ---------------- weight prep ----------------
__global__ __launch_bounds__(256) void k_prep_w0(
    const float* __restrict__ wi0, const float* __restrict__ bi0,
    const float* __restrict__ wh0, const float* __restrict__ bh0,
    uint16_t* __restrict__ W0c, float* __restrict__ b0) {
  int r = blockIdx.x;            // interleaved output row: unit j, gate p
  int p = r & 3, j = r >> 2;
  int src = p * 1024 + j;
  const float* wi = wi0 + (size_t)src * 319;
  const float* wh = wh0 + (size_t)src * 1024;
  uint16_t* dst = W0c + (size_t)r * 1344;
  for (int k = threadIdx.x; k < 1344; k += 256) {
    float v;
    if (k < 319) v = wi[k];
    else if (k == 319) v = 0.0f;
    else v = wh[k - 320];
    dst[k] = f2bf(v);
  }
  if (threadIdx.x == 0) b0[r] = bi0[src] + bh0[src];
}

__global__ __launch_bounds__(256) void k_prep_w1(
    const float* __restrict__ wi1, const float* __restrict__ bi1,
    const float* __restrict__ wh1, const float* __restrict__ bh1,
    uint16_t* __restrict__ W1c, float* __restrict__ b1) {
  int r = blockIdx.x;
  int p = r & 3, j = r >> 2;
  int src = p * 1024 + j;
  const float* wi = wi1 + (size_t)src * 1024;
  const float* wh = wh1 + (size_t)src * 1024;
  uint16_t* dst = W1c + (size_t)r * 2048;
  for (int k = threadIdx.x; k < 2048; k += 256) {
    float v = (k < 1024) ? wi[k] : wh[k - 1024];
    dst[k] = f2bf(v);
  }
  if (threadIdx.x == 0) b1[r] = bi1[src] + bh1[src];
}

__global__ __launch_bounds__(256) void k_init(
    const float* __restrict__ h_init, const float* __restrict__ c_init,
    uint16_t* __restrict__ h0_slot0, float* __restrict__ c_state) {
  int i = blockIdx.x * 256 + threadIdx.x;  // 262144 = 256*1024
  h0_slot0[i] = f2bf(h_init[i]);           // layer0 slice of h_init
  c_state[i] = c_init[i];
}

// ---------------- embedding + concat -> x_bf ----------------
__global__ __launch_bounds__(256) void k_embed(
    const int* __restrict__ tokens, const float* __restrict__ casing,
    const float* __restrict__ pos, const float* __restrict__ emb,
    uint16_t* __restrict__ x_bf) {
  int row = blockIdx.x * 4 + (threadIdx.x >> 6);  // (t*256+b)
  int l = threadIdx.x & 63;
  int tok = tokens[row];
  const float* er = emb + (size_t)tok * 300;
  uint16_t* xr = x_bf + (size_t)row * 320;
#pragma unroll
  for (int c0 = 0; c0 < 320; c0 += 64) {
    int c = c0 + l;
    float v;
    if (c < 300) v = er[c];
    else if (c < 307) v = casing[(size_t)row * 7 + (c - 300)];
    else if (c < 319) v = pos[(size_t)row * 12 + (c - 307)];
    else v = 0.0f;
    xr[c] = f2bf(v);
  }
}

// ---------------- layer0 sequential step ----------------
// GEMM [256 x 1344] @ [4096 x 1344]^T, tile 64x64, 4 waves (2x2), fused cell.
__global__ __launch_bounds__(256) void k_step(
    const uint16_t* __restrict__ x_t, const uint16_t* __restrict__ W0c,
    const float* __restrict__ b0, const uint16_t* __restrict__ h0_in,
    uint16_t* __restrict__ h0_out, uint16_t* __restrict__ c0_out,
    float* __restrict__ c_state) {
  __shared__ __align__(16) uint16_t As[64 * 32];
  __shared__ __align__(16) uint16_t Bs[64 * 32];
  __shared__ __align__(16) float epi[4][16][40];
  int tid = threadIdx.x;
  int w = tid >> 6, l = tid & 63;
  int wr = w >> 1, wc = w & 1;
  int Mb = blockIdx.x * 64;   // batch tile
  int Nb = blockIdx.y * 64;   // output-col tile (gate-interleaved)
  f32x4 acc[2][2] = {};

  int srow = w * 16 + (l >> 2);
  int sc = (l & 3) ^ ((l >> 3) & 3);  // global chunk for this lane's LDS slot
  int bA = Mb + srow;
  const uint16_t* xrow = x_t + (size_t)bA * 320;
  const uint16_t* hrow = h0_in + (size_t)bA * 1024;
  const uint16_t* wrow = W0c + (size_t)(Nb + srow) * 1344;
  uint16_t* AsW = As + w * 512;
  uint16_t* BsW = Bs + w * 512;

  for (int kt = 0; kt < 42; ++kt) {
    int kg = kt * 32 + sc * 8;
    const uint16_t* srcA = (kg < 320) ? (xrow + kg) : (hrow + (kg - 320));
    gload_lds16(srcA, AsW);
    gload_lds16(wrow + kg, BsW);
    __syncthreads();
    bf16x8 a0 = lds_frag(As, wr * 32 + (l & 15), l >> 4);
    bf16x8 a1 = lds_frag(As, wr * 32 + 16 + (l & 15), l >> 4);
    bf16x8 q0 = lds_frag(Bs, wc * 32 + (l & 15), l >> 4);
    bf16x8 q1 = lds_frag(Bs, wc * 32 + 16 + (l & 15), l >> 4);
    acc[0][0] = mfma16(a0, q0, acc[0][0]);
    acc[0][1] = mfma16(a0, q1, acc[0][1]);
    acc[1][0] = mfma16(a1, q0, acc[1][0]);
    acc[1][1] = mfma16(a1, q1, acc[1][1]);
    __syncthreads();
  }

  // fused LSTM cell epilogue (per-wave LDS scratch)
  int jbase = (Nb + wc * 32) >> 2;
#pragma unroll
  for (int m = 0; m < 2; ++m) {
#pragma unroll
    for (int n = 0; n < 2; ++n)
#pragma unroll
      for (int r = 0; r < 4; ++r)
        epi[w][(l >> 4) * 4 + r][n * 16 + (l & 15)] = acc[m][n][r];
    asm volatile("s_waitcnt lgkmcnt(0)" ::: "memory");
#pragma unroll
    for (int it = 0; it < 2; ++it) {
      int pp = it * 64 + l;
      int rr = pp >> 3, j = pp & 7;
      f32x4 q = *(const f32x4*)&epi[w][rr][j * 4];
      int colg = Nb + wc * 32 + j * 4;
      f32x4 bv = *(const f32x4*)&b0[colg];
      float vi = sigmoidf_(q[0] + bv[0]);
      float vf = sigmoidf_(q[1] + bv[1]);
      float vo = sigmoidf_(q[2] + bv[2]);
      float vg = tanhf_(q[3] + bv[3]);
      int bg = Mb + wr * 32 + m * 16 + rr;
      int jg = jbase + j;
      size_t sidx = (size_t)bg * 1024 + jg;
      float cold = c_state[sidx];
      float cn = vf * cold + vi * vg;
      float hh = vo * tanhf_(cn);
      c_state[sidx] = cn;
      c0_out[sidx] = f2bf(cn);
      h0_out[sidx] = f2bf(hh);
    }
    asm volatile("s_waitcnt lgkmcnt(0)" ::: "memory");
  }
}

// ---------------- layer1 GEMM over one chunk ----------------
// rows = CH*256; A row (t,b) = [h0(t,b) | h0(t,255-b)]  (h0 = post-step slot).
// tile 128x128, 4 waves (2x2) x (4x4 frags), fused cell epilogue.
// grid (32, 2*CH).  h0ring slot (t+1)%ringH; c0ring slot t%CH; h1 local slot.
__global__ __launch_bounds__(256) void k_l1gemm(
    const uint16_t* __restrict__ h0ring, int ringH, int t0,
    const uint16_t* __restrict__ W1c, const float* __restrict__ b1,
    const uint16_t* __restrict__ c0ring, int CH,
    uint16_t* __restrict__ h1buf) {
  __shared__ __align__(16) uint16_t As[128 * 32];
  __shared__ __align__(16) uint16_t Bs[128 * 32];
  __shared__ __align__(16) float epi[4][16][68];
  int tid = threadIdx.x;
  int w = tid >> 6, l = tid & 63;
  int wr = w >> 1, wc = w & 1;
  int Mb = blockIdx.y * 128, Nb = blockIdx.x * 128;
  int tl = Mb >> 8;            // chunk-local t
  int t = t0 + tl;
  int bbase = Mb & 255;        // 0 or 128
  const uint16_t* hrow = h0ring + (size_t)((t + 1) % ringH) * SLOT;
  const uint16_t* c0s = c0ring + (size_t)(t % CH) * SLOT;
  uint16_t* h1s = h1buf + (size_t)tl * SLOT;
  f32x4 acc[4][4] = {};

  int sc = (l & 3) ^ ((l >> 3) & 3);
  int srow0 = (w * 2 + 0) * 16 + (l >> 2);
  int srow1 = (w * 2 + 1) * 16 + (l >> 2);
  const uint16_t* hA0n = hrow + (size_t)(bbase + srow0) * 1024;
  const uint16_t* hA0f = hrow + (size_t)(255 - (bbase + srow0)) * 1024;
  const uint16_t* hA1n = hrow + (size_t)(bbase + srow1) * 1024;
  const uint16_t* hA1f = hrow + (size_t)(255 - (bbase + srow1)) * 1024;
  const uint16_t* wB0 = W1c + (size_t)(Nb + srow0) * 2048;
  const uint16_t* wB1 = W1c + (size_t)(Nb + srow1) * 2048;
  uint16_t* AsW0 = As + (w * 2 + 0) * 512;
  uint16_t* AsW1 = As + (w * 2 + 1) * 512;
  uint16_t* BsW0 = Bs + (w * 2 + 0) * 512;
  uint16_t* BsW1 = Bs + (w * 2 + 1) * 512;

  for (int kt = 0; kt < 64; ++kt) {
    int kg = kt * 32 + sc * 8;
    const uint16_t* sA0 = (kg < 1024) ? (hA0n + kg) : (hA0f + (kg - 1024));
    const uint16_t* sA1 = (kg < 1024) ? (hA1n + kg) : (hA1f + (kg - 1024));
    gload_lds16(sA0, AsW0);
    gload_lds16(sA1, AsW1);
    gload_lds16(wB0 + kg, BsW0);
    gload_lds16(wB1 + kg, BsW1);
    __syncthreads();
    bf16x8 a[4], q[4];
#pragma unroll
    for (int m = 0; m < 4; ++m) a[m] = lds_frag(As, wr * 64 + m * 16 + (l & 15), l >> 4);
#pragma unroll
    for (int n = 0; n < 4; ++n) q[n] = lds_frag(Bs, wc * 64 + n * 16 + (l & 15), l >> 4);
#pragma unroll
    for (int m = 0; m < 4; ++m)
#pragma unroll
      for (int n = 0; n < 4; ++n) acc[m][n] = mfma16(a[m], q[n], acc[m][n]);
    __syncthreads();
  }

  int jbase = (Nb + wc * 64) >> 2;
#pragma unroll
  for (int m = 0; m < 4; ++m) {
#pragma unroll
    for (int n = 0; n < 4; ++n)
#pragma unroll
      for (int r = 0; r < 4; ++r)
        epi[w][(l >> 4) * 4 + r][n * 16 + (l & 15)] = acc[m][n][r];
    asm volatile("s_waitcnt lgkmcnt(0)" ::: "memory");
#pragma unroll
    for (int it = 0; it < 4; ++it) {
      int pp = it * 64 + l;
      int rr = pp >> 4, j = pp & 15;
      f32x4 q = *(const f32x4*)&epi[w][rr][j * 4];
      int colg = Nb + wc * 64 + j * 4;
      f32x4 bv = *(const f32x4*)&b1[colg];
      float vi = sigmoidf_(q[0] + bv[0]);
      float vf = sigmoidf_(q[1] + bv[1]);
      float vo = sigmoidf_(q[2] + bv[2]);
      float vg = tanhf_(q[3] + bv[3]);
      int rowl = wr * 64 + m * 16 + rr;
      int b = bbase + rowl;
      int jg = jbase + j;
      float c0v = bf2f(c0s[(size_t)(255 - b) * 1024 + jg]);
      float cn = vf * c0v + vi * vg;
      float hh = vo * tanhf_(cn);
      h1s[(size_t)b * 1024 + jg] = f2bf(hh);
    }
    asm volatile("s_waitcnt lgkmcnt(0)" ::: "memory");
  }
}

// ---------------- decoder over one chunk ----------------
// grid CH*64 blocks (4 rows/block).  h0 from ring slot (t+1)%ringH.
__global__ __launch_bounds__(256) void k_decode(
    const uint16_t* __restrict__ h0ring, int ringH, int t0,
    const uint16_t* __restrict__ h1buf,
    const float* __restrict__ dec_w, const float* __restrict__ dec_b,
    float* __restrict__ out) {
  int rowl = blockIdx.x * 4 + (threadIdx.x >> 6);  // chunk-local row
  int l = threadIdx.x & 63;
  int tl = rowl >> 8, b = rowl & 255;
  int t = t0 + tl;
  const uint16_t* h0 = h0ring + (size_t)((t + 1) % ringH) * SLOT + (size_t)b * 1024;
  const uint16_t* h1 = h1buf + (size_t)rowl * 1024;
  float acc[13];
#pragma unroll
  for (int c = 0; c < 13; ++c) acc[c] = 0.0f;
#pragma unroll
  for (int part = 0; part < 2; ++part) {
    const uint16_t* h = part ? h1 : h0;
    const float* wb = dec_w + part * 1024 + (size_t)l * 16;
    float hv[16];
    const bf16x8* hp = (const bf16x8*)(h + l * 16);
    bf16x8 v0 = hp[0];
    bf16x8 v1 = hp[1];
#pragma unroll
    for (int jj = 0; jj < 8; ++jj) {
      hv[jj] = bf2f((uint16_t)v0[jj]);
      hv[8 + jj] = bf2f((uint16_t)v1[jj]);
    }
#pragma unroll
    for (int c = 0; c < 13; ++c) {
      const float* wc = wb + (size_t)c * 2048;
      float s = 0.0f;
#pragma unroll
      for (int jj = 0; jj < 16; ++jj) s += hv[jj] * wc[jj];
      acc[c] += s;
    }
  }
#pragma unroll
  for (int c = 0; c < 13; ++c) {
    float v = acc[c];
#pragma unroll
    for (int off = 32; off > 0; off >>= 1) v += __shfl_xor(v, off, 64);
    acc[c] = v;
  }
  if (l == 0) {
    float* orow = out + ((size_t)t * 256 + b) * 13;
#pragma unroll
    for (int c = 0; c < 13; ++c) orow[c] = acc[c] + dec_b[c];
  }
}

// ---------------- host ----------------
extern "C" void kernel_launch(void* const* d_in, const int* in_sizes, int n_in,
                              void* d_out, int out_size, void* d_ws, size_t ws_size,
                              hipStream_t stream) {
  const int* tokens = (const int*)d_in[0];
  const float* casing = (const float*)d_in[1];
  const float* pos = (const float*)d_in[2];
  const float* emb = (const float*)d_in[3];
  const float* wi0 = (const float*)d_in[4];
  const float* bi0 = (const float*)d_in[5];
  const float* wh0 = (const float*)d_in[6];
  const float* bh0 = (const float*)d_in[7];
  const float* wi1 = (const float*)d_in[8];
  const float* bi1 = (const float*)d_in[9];
  const float* wh1 = (const float*)d_in[10];
  const float* bh1 = (const float*)d_in[11];
  const float* dec_w = (const float*)d_in[12];
  const float* dec_b = (const float*)d_in[13];
  const float* h_init = (const float*)d_in[14];
  const float* c_init = (const float*)d_in[15];
  float* out = (float*)d_out;
  (void)in_sizes; (void)n_in; (void)out_size;

  char* ws = (char*)d_ws;
  size_t off = 0;
  auto alloc = [&](size_t bytes) {
    char* p = ws + off;
    off += (bytes + 255) & ~(size_t)255;
    return p;
  };
  // fixed buffers (~71 MB)
  uint16_t* W0c = (uint16_t*)alloc(4096ull * 1344 * 2);
  float* b0 = (float*)alloc(4096 * 4);
  uint16_t* W1c = (uint16_t*)alloc(4096ull * 2048 * 2);
  float* b1 = (float*)alloc(4096 * 4);
  uint16_t* x_bf = (uint16_t*)alloc(65536ull * 320 * 2);
  float* c_st = (float*)alloc(SLOT * 4);

  // choose chunk size: need (CH+1) + CH + CH ring slots of SLOT*2 bytes
  const size_t SB = ((SLOT * 2 + 255) & ~(size_t)255);
  int CH = 0;
  for (int c = 64; c >= 1; c >>= 1) {
    if (off + (size_t)(3 * c + 1) * SB + 4096 <= ws_size) { CH = c; break; }
  }
  if (CH == 0) return;  // ws too small (diagnostic: poisoned output)
  int ringH = CH + 1;
  uint16_t* h0ring = (uint16_t*)alloc((size_t)ringH * SB);
  uint16_t* c0ring = (uint16_t*)alloc((size_t)CH * SB);
  uint16_t* h1buf = (uint16_t*)alloc((size_t)CH * SB);

  k_prep_w0<<<4096, 256, 0, stream>>>(wi0, bi0, wh0, bh0, W0c, b0);
  k_prep_w1<<<4096, 256, 0, stream>>>(wi1, bi1, wh1, bh1, W1c, b1);
  k_embed<<<16384, 256, 0, stream>>>(tokens, casing, pos, emb, x_bf);
  k_init<<<1024, 256, 0, stream>>>(h_init, c_init, h0ring, c_st);

  const size_t SE = SB / 2;  // slot stride in uint16 elements
  for (int t0 = 0; t0 < 256; t0 += CH) {
    for (int t = t0; t < t0 + CH; ++t) {
      k_step<<<dim3(4, 64), 256, 0, stream>>>(
          x_bf + (size_t)t * 81920, W0c, b0,
          h0ring + (size_t)(t % ringH) * SE,
          h0ring + (size_t)((t + 1) % ringH) * SE,
          c0ring + (size_t)(t % CH) * SE, c_st);
    }
    k_l1gemm<<<dim3(32, 2 * CH), 256, 0, stream>>>(
        h0ring, ringH, t0, W1c, b1, c0ring, CH, h1buf);
    k_decode<<<CH * 64, 256, 0, stream>>>(
        h0ring, ringH, t0, h1buf, dec_w, dec_b, out);
  }
}